// Round 1
// baseline (201.513 us; speedup 1.0000x reference)
//
#include <hip/hip_runtime.h>
#include <stdint.h>
#include <stddef.h>

// ---------------- problem constants ----------------
#define HIDDEN 1024
#define NHEADS 16
#define HDIM   64
#define BS     8
#define SEQ    1024
#define MTOT   (BS*SEQ)          // 8192 rows
#define QKV_T  ((size_t)MTOT*HIDDEN)  // 8,388,608 elements per tensor

typedef short    bf16x8 __attribute__((ext_vector_type(8)));
typedef float    f32x4  __attribute__((ext_vector_type(4)));
typedef uint16_t u16x4  __attribute__((ext_vector_type(4)));

__device__ __forceinline__ uint16_t f2bf(float f) {
  union { float f; uint32_t u; } c; c.f = f;
  uint32_t u = c.u + 0x7FFFu + ((c.u >> 16) & 1u);   // RNE
  return (uint16_t)(u >> 16);
}

// ================= kernel 1: fp32 -> bf16 convert =================
// hs: 8M floats -> hsb ; Wq|Wk|Wv: 3x1M floats -> wcat (rows n, cols k)
__global__ __launch_bounds__(256) void cvt_kernel(
    const float* __restrict__ hs, const float* __restrict__ wq,
    const float* __restrict__ wk, const float* __restrict__ wv,
    uint16_t* __restrict__ hsb, uint16_t* __restrict__ wcat)
{
  const int i4 = blockIdx.x * 256 + threadIdx.x;      // 2,883,584 total
  f32x4 v;
  u16x4 o;
  if (i4 < 2097152) {                                  // hidden states
    v = *((const f32x4*)hs + i4);
    o[0]=f2bf(v[0]); o[1]=f2bf(v[1]); o[2]=f2bf(v[2]); o[3]=f2bf(v[3]);
    *((u16x4*)hsb + i4) = o;
  } else {                                             // weights
    int j4 = i4 - 2097152;                             // [0, 786432)
    int w  = j4 >> 18;                                 // 262144 float4 per W
    int r4 = j4 & 262143;
    const float* src = (w == 0) ? wq : ((w == 1) ? wk : wv);
    v = *((const f32x4*)src + r4);
    o[0]=f2bf(v[0]); o[1]=f2bf(v[1]); o[2]=f2bf(v[2]); o[3]=f2bf(v[3]);
    *((u16x4*)wcat + j4) = o;
  }
}

// ================= kernel 2: fused QKV GEMM =================
// C[m,n] = sum_k hsb[m,k]*wcat[n,k] + bias[n]; n in [0,3072)
// 128x128 tile, BK=32, 4 waves (2x2 of 64x64), mfma 16x16x32 bf16.
// LDS XOR-swizzled at 16B granules: slot = (g ^ ((row>>1)&3)) & 3.
__global__ __launch_bounds__(256) void gemm_qkv(
    const uint16_t* __restrict__ hsb, const uint16_t* __restrict__ wcat,
    const float* __restrict__ bq, const float* __restrict__ bk,
    const float* __restrict__ bv, uint16_t* __restrict__ qkvb)
{
  __shared__ uint16_t Alds[2][128*32];
  __shared__ uint16_t Blds[2][128*32];

  const int bid = blockIdx.x;                 // 1536 blocks, %8==0 -> bijective
  const int wg  = (bid & 7) * 192 + (bid >> 3);   // XCD swizzle
  const int tm  = wg / 24, tn = wg % 24;
  const int m0  = tm * 128, n0 = tn * 128;
  const int t   = threadIdx.x;
  const int l   = t & 63, w = t >> 6;
  const int wm  = w >> 1, wn = w & 1;

  const int row0 = t >> 2;          // chunk row (ia=0: rows 0..63; ia=1: +64)
  const int g0   = t & 3;           // 16B granule within the 64B row
  const int gsw  = (g0 ^ ((row0 >> 1) & 3)) & 3;   // same for row0 and row0+64

  f32x4 acc[4][4];
#pragma unroll
  for (int i = 0; i < 4; i++)
#pragma unroll
    for (int j = 0; j < 4; j++) acc[i][j] = (f32x4){0.f,0.f,0.f,0.f};

  bf16x8 ra0, ra1, rb0, rb1;

  auto LOADT = [&](int kt) {
    const uint16_t* Ab = hsb  + (size_t)m0 * HIDDEN + kt * 32;
    const uint16_t* Bb = wcat + (size_t)n0 * HIDDEN + kt * 32;
    ra0 = *(const bf16x8*)(Ab + (size_t)row0        * HIDDEN + g0 * 8);
    ra1 = *(const bf16x8*)(Ab + (size_t)(row0 + 64) * HIDDEN + g0 * 8);
    rb0 = *(const bf16x8*)(Bb + (size_t)row0        * HIDDEN + g0 * 8);
    rb1 = *(const bf16x8*)(Bb + (size_t)(row0 + 64) * HIDDEN + g0 * 8);
  };
  auto WRITET = [&](int buf) {
    *(bf16x8*)&Alds[buf][ row0       * 32 + gsw * 8] = ra0;
    *(bf16x8*)&Alds[buf][(row0 + 64) * 32 + gsw * 8] = ra1;
    *(bf16x8*)&Blds[buf][ row0       * 32 + gsw * 8] = rb0;
    *(bf16x8*)&Blds[buf][(row0 + 64) * 32 + gsw * 8] = rb1;
  };
  auto COMPUTE = [&](int buf) {
    bf16x8 af[4], bfr[4];
    const int G = l >> 4;
#pragma unroll
    for (int i = 0; i < 4; i++) {
      int ar = wm * 64 + i * 16 + (l & 15);
      int gs = (G ^ ((ar >> 1) & 3)) & 3;
      af[i] = *(const bf16x8*)&Alds[buf][ar * 32 + gs * 8];
    }
#pragma unroll
    for (int j = 0; j < 4; j++) {
      int br = wn * 64 + j * 16 + (l & 15);
      int gs = (G ^ ((br >> 1) & 3)) & 3;
      bfr[j] = *(const bf16x8*)&Blds[buf][br * 32 + gs * 8];
    }
#pragma unroll
    for (int i = 0; i < 4; i++)
#pragma unroll
      for (int j = 0; j < 4; j++)
        acc[i][j] = __builtin_amdgcn_mfma_f32_16x16x32_bf16(af[i], bfr[j], acc[i][j], 0, 0, 0);
  };

  LOADT(0); WRITET(0); __syncthreads();
#pragma unroll 1
  for (int kt = 0; kt < 32; ++kt) {
    if (kt < 31) LOADT(kt + 1);       // issue next-tile loads (latency hides under MFMA)
    COMPUTE(kt & 1);
    if (kt < 31) WRITET((kt + 1) & 1);
    __syncthreads();
  }

  // epilogue: bias + bf16, scatter into Q/K/V [b,h,s,d]
#pragma unroll
  for (int j = 0; j < 4; j++) {
    int n     = n0 + wn * 64 + j * 16 + (l & 15);
    int which = n >> 10, nn = n & 1023;
    const float* bp = (which == 0) ? bq : ((which == 1) ? bk : bv);
    float bias = bp[nn];
    int hh = nn >> 6, dd = nn & 63;
    uint16_t* outp = qkvb + (size_t)which * QKV_T;
#pragma unroll
    for (int i = 0; i < 4; i++) {
#pragma unroll
      for (int r = 0; r < 4; r++) {
        int m  = m0 + wm * 64 + i * 16 + (l >> 4) * 4 + r;
        int b_ = m >> 10, s_ = m & 1023;
        outp[(((size_t)(b_ * NHEADS + hh)) * SEQ + s_) * HDIM + dd] =
            f2bf(acc[i][j][r] + bias);
      }
    }
  }
}

// ================= kernel 3: flash attention =================
// Block: one (b,h), 64 Q-rows (4 waves x 16). K/V tiles 64x64 in LDS.
// K swizzled row-major; V stored transposed (Vt[d][k]) + swizzled so PV
// B-fragments are contiguous ds_read_b128. Online softmax, fp32 out.
__global__ __launch_bounds__(256) void attn_kernel(
    const uint16_t* __restrict__ qkvb, const float* __restrict__ mask,
    float* __restrict__ out)
{
  __shared__ uint16_t Klds[64 * 64];
  __shared__ uint16_t Vlds[64 * 64];     // transposed: [d][k]
  __shared__ uint16_t Plds[4][16 * 64];  // per-wave P tile
  __shared__ float    mlds[SEQ];

  const int bid = blockIdx.x;                 // 2048 blocks, %8==0
  const int wg  = (bid & 7) * 256 + (bid >> 3);   // XCD swizzle: 16 bh per XCD chunk
  const int bh  = wg >> 4;
  const int qt  = wg & 15;
  const int b   = bh >> 4, h = bh & 15;

  const uint16_t* Qb = qkvb              + (size_t)bh * SEQ * HDIM;
  const uint16_t* Kb = qkvb + QKV_T      + (size_t)bh * SEQ * HDIM;
  const uint16_t* Vb = qkvb + 2 * QKV_T  + (size_t)bh * SEQ * HDIM;

  const int t = threadIdx.x, l = t & 63, w = t >> 6;

  for (int i = t; i < SEQ; i += 256) mlds[i] = mask[b * SEQ + i];

  // Q fragments (16 rows per wave), A-frag layout: row=l&15, k=(l>>4)*8
  const int q0 = qt * 64 + w * 16;
  bf16x8 qf[2];
#pragma unroll
  for (int k0 = 0; k0 < 2; k0++)
    qf[k0] = *(const bf16x8*)(Qb + (size_t)(q0 + (l & 15)) * HDIM + k0 * 32 + (l >> 4) * 8);

  f32x4 O[4];
#pragma unroll
  for (int jd = 0; jd < 4; jd++) O[jd] = (f32x4){0.f,0.f,0.f,0.f};
  float mrow[4] = {-1e30f, -1e30f, -1e30f, -1e30f};
  float lrow[4] = {0.f, 0.f, 0.f, 0.f};
  const float SCALE = 0.125f;   // 1/sqrt(64)

  __syncthreads();

#pragma unroll 1
  for (int kt = 0; kt < 16; ++kt) {
    // ---- stage K tile (row-swizzled): slot = (g ^ (row&7)) & 7 ----
#pragma unroll
    for (int ia = 0; ia < 2; ia++) {
      int row = t >> 2;
      int g   = (t & 3) + ia * 4;
      bf16x8 kv = *(const bf16x8*)(Kb + (size_t)(kt * 64 + row) * HDIM + g * 8);
      int gs = (g ^ (row & 7)) & 7;
      *(bf16x8*)&Klds[row * 64 + gs * 8] = kv;
    }
    // ---- stage V transposed: Vt[d][k], slot = ((k>>3) ^ (d&7)) & 7 ----
#pragma unroll
    for (int ia = 0; ia < 2; ia++) {
      int dg = w + ia * 4;
      bf16x8 vv = *(const bf16x8*)(Vb + (size_t)(kt * 64 + l) * HDIM + dg * 8);
#pragma unroll
      for (int j = 0; j < 8; j++) {
        int d  = dg * 8 + j;
        int gs = ((l >> 3) ^ (d & 7)) & 7;
        Vlds[d * 64 + gs * 8 + (l & 7)] = (uint16_t)vv[j];
      }
    }
    __syncthreads();

    // ---- S = Q K^T (16x64 per wave) ----
    f32x4 sc[4];
#pragma unroll
    for (int jn = 0; jn < 4; jn++) sc[jn] = (f32x4){0.f,0.f,0.f,0.f};
#pragma unroll
    for (int k0 = 0; k0 < 2; k0++) {
#pragma unroll
      for (int jn = 0; jn < 4; jn++) {
        int kr = jn * 16 + (l & 15);
        int G  = k0 * 4 + (l >> 4);
        int gs = (G ^ (kr & 7)) & 7;
        bf16x8 kf = *(const bf16x8*)&Klds[kr * 64 + gs * 8];
        sc[jn] = __builtin_amdgcn_mfma_f32_16x16x32_bf16(qf[k0], kf, sc[jn], 0, 0, 0);
      }
    }

    // ---- online softmax (rows = (l>>4)*4 + r, cols = jn*16 + (l&15)) ----
    float tm4[4] = {-1e30f, -1e30f, -1e30f, -1e30f};
#pragma unroll
    for (int jn = 0; jn < 4; jn++) {
      float mv = mlds[kt * 64 + jn * 16 + (l & 15)];
#pragma unroll
      for (int r = 0; r < 4; r++) {
        float sv = sc[jn][r] * SCALE + mv;
        sc[jn][r] = sv;
        tm4[r] = fmaxf(tm4[r], sv);
      }
    }
#pragma unroll
    for (int off = 1; off <= 8; off <<= 1) {
#pragma unroll
      for (int r = 0; r < 4; r++)
        tm4[r] = fmaxf(tm4[r], __shfl_xor(tm4[r], off));
    }
    float fs4[4], ps4[4] = {0.f, 0.f, 0.f, 0.f};
#pragma unroll
    for (int r = 0; r < 4; r++) {
      float mn = fmaxf(mrow[r], tm4[r]);
      fs4[r] = __expf(mrow[r] - mn);    // mrow=-1e30 -> 0, no NaN
      mrow[r] = mn;
    }
#pragma unroll
    for (int jn = 0; jn < 4; jn++) {
#pragma unroll
      for (int r = 0; r < 4; r++) {
        float p = __expf(sc[jn][r] - mrow[r]);
        ps4[r] += p;
        int prw  = (l >> 4) * 4 + r;
        int pcol = jn * 16 + (l & 15);
        int gs   = ((pcol >> 3) ^ (prw & 7)) & 7;
        Plds[w][prw * 64 + gs * 8 + (pcol & 7)] = f2bf(p);
      }
    }
#pragma unroll
    for (int off = 1; off <= 8; off <<= 1) {
#pragma unroll
      for (int r = 0; r < 4; r++)
        ps4[r] += __shfl_xor(ps4[r], off);
    }
#pragma unroll
    for (int r = 0; r < 4; r++) lrow[r] = lrow[r] * fs4[r] + ps4[r];
#pragma unroll
    for (int jd = 0; jd < 4; jd++)
#pragma unroll
      for (int r = 0; r < 4; r++) O[jd][r] *= fs4[r];

    __syncthreads();   // P visible (covers cross-lane LDS dep)

    // ---- O += P V ----
#pragma unroll
    for (int k0 = 0; k0 < 2; k0++) {
      int pr  = l & 15;
      int G   = k0 * 4 + (l >> 4);
      int gsp = (G ^ (pr & 7)) & 7;
      bf16x8 pf = *(const bf16x8*)&Plds[w][pr * 64 + gsp * 8];
#pragma unroll
      for (int jd = 0; jd < 4; jd++) {
        int dr  = jd * 16 + (l & 15);
        int gsv = (G ^ (dr & 7)) & 7;
        bf16x8 vf = *(const bf16x8*)&Vlds[dr * 64 + gsv * 8];
        O[jd] = __builtin_amdgcn_mfma_f32_16x16x32_bf16(pf, vf, O[jd], 0, 0, 0);
      }
    }
    __syncthreads();   // all reads done before next stage overwrites
  }

  // ---- epilogue: normalize + write out[b, s, h*64+d] ----
#pragma unroll
  for (int jd = 0; jd < 4; jd++) {
#pragma unroll
    for (int r = 0; r < 4; r++) {
      int srow = q0 + (l >> 4) * 4 + r;
      out[((size_t)(b * SEQ + srow)) * HIDDEN + h * HDIM + jd * 16 + (l & 15)] =
          O[jd][r] / lrow[r];
    }
  }
}

// ================= host launcher =================
extern "C" void kernel_launch(void* const* d_in, const int* in_sizes, int n_in,
                              void* d_out, int out_size, void* d_ws, size_t ws_size,
                              hipStream_t stream) {
  const float* hs   = (const float*)d_in[0];
  const float* mask = (const float*)d_in[1];
  const float* Wq   = (const float*)d_in[2];
  const float* bq   = (const float*)d_in[3];
  const float* Wk   = (const float*)d_in[4];
  const float* bk   = (const float*)d_in[5];
  const float* Wv   = (const float*)d_in[6];
  const float* bv   = (const float*)d_in[7];
  float* out = (float*)d_out;

  // workspace layout (bytes): hsb 16MB | wcat 6MB | qkv 48MB  (= 70MB)
  uint16_t* hsb  = (uint16_t*)d_ws;
  uint16_t* wcat = (uint16_t*)((char*)d_ws + (size_t)16777216);
  uint16_t* qkvb = (uint16_t*)((char*)d_ws + (size_t)23068672);

  cvt_kernel<<<11264, 256, 0, stream>>>(hs, Wq, Wk, Wv, hsb, wcat);
  gemm_qkv<<<1536, 256, 0, stream>>>(hsb, wcat, bq, bk, bv, qkvb);
  attn_kernel<<<2048, 256, 0, stream>>>(qkvb, mask, out);
}

// Round 2
// 178.507 us; speedup vs baseline: 1.1289x; 1.1289x over previous
//
#include <hip/hip_runtime.h>
#include <stdint.h>
#include <stddef.h>

// ---------------- problem constants ----------------
#define HIDDEN 1024
#define NHEADS 16
#define HDIM   64
#define BS     8
#define SEQ    1024
#define MTOT   (BS*SEQ)               // 8192 rows
#define QKV_T  ((size_t)MTOT*HIDDEN)

typedef short    bf16x8 __attribute__((ext_vector_type(8)));
typedef float    f32x4  __attribute__((ext_vector_type(4)));
typedef uint16_t u16x4  __attribute__((ext_vector_type(4)));

__device__ __forceinline__ uint16_t f2bf(float f) {
  union { float f; uint32_t u; } c; c.f = f;
  uint32_t u = c.u + 0x7FFFu + ((c.u >> 16) & 1u);   // RNE
  return (uint16_t)(u >> 16);
}

__device__ __forceinline__ float exp2fast(float x) {
#if __has_builtin(__builtin_amdgcn_exp2f)
  return __builtin_amdgcn_exp2f(x);
#else
  return __expf(x * 0.69314718056f);
#endif
}

// ================= kernel 1: fp32 -> bf16 convert =================
__global__ __launch_bounds__(256) void cvt_kernel(
    const float* __restrict__ hs, const float* __restrict__ wq,
    const float* __restrict__ wk, const float* __restrict__ wv,
    uint16_t* __restrict__ hsb, uint16_t* __restrict__ wcat)
{
  const int i4 = blockIdx.x * 256 + threadIdx.x;      // 2,883,584 total
  f32x4 v;
  u16x4 o;
  if (i4 < 2097152) {                                  // hidden states
    v = *((const f32x4*)hs + i4);
    o[0]=f2bf(v[0]); o[1]=f2bf(v[1]); o[2]=f2bf(v[2]); o[3]=f2bf(v[3]);
    *((u16x4*)hsb + i4) = o;
  } else {                                             // weights
    int j4 = i4 - 2097152;                             // [0, 786432)
    int w  = j4 >> 18;                                  // 262144 float4 per W
    int r4 = j4 & 262143;
    const float* src = (w == 0) ? wq : ((w == 1) ? wk : wv);
    v = *((const f32x4*)src + r4);
    o[0]=f2bf(v[0]); o[1]=f2bf(v[1]); o[2]=f2bf(v[2]); o[3]=f2bf(v[3]);
    *((u16x4*)wcat + j4) = o;
  }
}

// ================= kernel 2: fused QKV GEMM =================
// C[m,n] = sum_k hsb[m,k]*wcat[n,k] + bias[n]; n in [0,3072)
// Epilogue: Q pre-scaled by 0.125*log2(e), written [b,h,s,d];
//           K written [b,h,s,d]; V written TRANSPOSED [b,h,d,s].
__global__ __launch_bounds__(256) void gemm_qkv(
    const uint16_t* __restrict__ hsb, const uint16_t* __restrict__ wcat,
    const float* __restrict__ bq, const float* __restrict__ bk,
    const float* __restrict__ bv, uint16_t* __restrict__ qbuf,
    uint16_t* __restrict__ kbuf, uint16_t* __restrict__ vtbuf)
{
  __shared__ uint16_t Alds[2][128*32];
  __shared__ uint16_t Blds[2][128*32];

  const int bid = blockIdx.x;                 // 1536 blocks, %8==0 -> bijective
  const int wg  = (bid & 7) * 192 + (bid >> 3);   // XCD swizzle
  const int tm  = wg / 24, tn = wg % 24;
  const int m0  = tm * 128, n0 = tn * 128;
  const int t   = threadIdx.x;
  const int l   = t & 63, w = t >> 6;
  const int wm  = w >> 1, wn = w & 1;

  const int row0 = t >> 2;
  const int g0   = t & 3;
  const int gsw  = (g0 ^ ((row0 >> 1) & 3)) & 3;

  f32x4 acc[4][4];
#pragma unroll
  for (int i = 0; i < 4; i++)
#pragma unroll
    for (int j = 0; j < 4; j++) acc[i][j] = (f32x4){0.f,0.f,0.f,0.f};

  bf16x8 ra0, ra1, rb0, rb1;

  auto LOADT = [&](int kt) {
    const uint16_t* Ab = hsb  + (size_t)m0 * HIDDEN + kt * 32;
    const uint16_t* Bb = wcat + (size_t)n0 * HIDDEN + kt * 32;
    ra0 = *(const bf16x8*)(Ab + (size_t)row0        * HIDDEN + g0 * 8);
    ra1 = *(const bf16x8*)(Ab + (size_t)(row0 + 64) * HIDDEN + g0 * 8);
    rb0 = *(const bf16x8*)(Bb + (size_t)row0        * HIDDEN + g0 * 8);
    rb1 = *(const bf16x8*)(Bb + (size_t)(row0 + 64) * HIDDEN + g0 * 8);
  };
  auto WRITET = [&](int buf) {
    *(bf16x8*)&Alds[buf][ row0       * 32 + gsw * 8] = ra0;
    *(bf16x8*)&Alds[buf][(row0 + 64) * 32 + gsw * 8] = ra1;
    *(bf16x8*)&Blds[buf][ row0       * 32 + gsw * 8] = rb0;
    *(bf16x8*)&Blds[buf][(row0 + 64) * 32 + gsw * 8] = rb1;
  };
  auto COMPUTE = [&](int buf) {
    bf16x8 af[4], bfr[4];
    const int G = l >> 4;
#pragma unroll
    for (int i = 0; i < 4; i++) {
      int ar = wm * 64 + i * 16 + (l & 15);
      int gs = (G ^ ((ar >> 1) & 3)) & 3;
      af[i] = *(const bf16x8*)&Alds[buf][ar * 32 + gs * 8];
    }
#pragma unroll
    for (int j = 0; j < 4; j++) {
      int br = wn * 64 + j * 16 + (l & 15);
      int gs = (G ^ ((br >> 1) & 3)) & 3;
      bfr[j] = *(const bf16x8*)&Blds[buf][br * 32 + gs * 8];
    }
#pragma unroll
    for (int i = 0; i < 4; i++)
#pragma unroll
      for (int j = 0; j < 4; j++)
        acc[i][j] = __builtin_amdgcn_mfma_f32_16x16x32_bf16(af[i], bfr[j], acc[i][j], 0, 0, 0);
  };

  LOADT(0); WRITET(0); __syncthreads();
#pragma unroll 1
  for (int kt = 0; kt < 32; ++kt) {
    if (kt < 31) LOADT(kt + 1);
    COMPUTE(kt & 1);
    if (kt < 31) WRITET((kt + 1) & 1);
    __syncthreads();
  }

  // epilogue
#pragma unroll
  for (int j = 0; j < 4; j++) {
    int n     = n0 + wn * 64 + j * 16 + (l & 15);
    int which = n >> 10, nn = n & 1023;    // `which` uniform per block
    const float* bp = (which == 0) ? bq : ((which == 1) ? bk : bv);
    float bias = bp[nn];
    int hh = nn >> 6, dd = nn & 63;
#pragma unroll
    for (int i = 0; i < 4; i++) {
#pragma unroll
      for (int r = 0; r < 4; r++) {
        int m  = m0 + wm * 64 + i * 16 + (l >> 4) * 4 + r;
        int b_ = m >> 10, s_ = m & 1023;
        float val = acc[i][j][r] + bias;
        size_t bhh = (size_t)(b_ * NHEADS + hh);
        if (which == 0)        // Q: fold softmax scale * log2(e)
          qbuf[(bhh * SEQ + s_) * HDIM + dd] = f2bf(val * 0.18033688011112042f);
        else if (which == 1)   // K
          kbuf[(bhh * SEQ + s_) * HDIM + dd] = f2bf(val);
        else                   // V transposed: [b,h,d,s]
          vtbuf[(bhh * HDIM + dd) * SEQ + s_] = f2bf(val);
      }
    }
  }
}

// ================= kernel 3: flash attention (swapped-operand) =================
// Block: one (b,h) x 128 Q-rows; 4 waves x QBLK=32. KVBLK=64.
// S^T = mfma(K,Q): lane holds P^T[k = jn*16+G*4+r][q = qi*16+(l&15)]
//   -> k-reduction: in-register + shfl_xor(16,32); P write: ds_write_b64.
// O^T = mfma(Vt,P): Vt from GEMM (pre-transposed), P from per-wave LDS.
// All LDS 16B-granule XOR-swizzled (slot ^= row&7): <=2-way conflicts.
__global__ __launch_bounds__(256) void attn_kernel(
    const uint16_t* __restrict__ qb, const uint16_t* __restrict__ kb,
    const uint16_t* __restrict__ vtb, const float* __restrict__ mask,
    float* __restrict__ out)
{
  __shared__ uint16_t Klds[64 * 64];
  __shared__ uint16_t Vlds[64 * 64];      // Vt tile: [d][k]
  __shared__ uint16_t Plds[4][32 * 64];   // per-wave P: [q][k]
  __shared__ float    mlds[SEQ];

  const int bid = blockIdx.x;                    // 1024 blocks, %8==0
  const int wg  = (bid & 7) * 128 + (bid >> 3);  // XCD swizzle
  const int bh  = wg >> 3;
  const int qt  = wg & 7;
  const int b   = bh >> 4, h = bh & 15;

  const uint16_t* Qg = qb  + (size_t)bh * SEQ * HDIM;
  const uint16_t* Kg = kb  + (size_t)bh * SEQ * HDIM;
  const uint16_t* Vg = vtb + (size_t)bh * HDIM * SEQ;

  const int t = threadIdx.x, l = t & 63, w = t >> 6;
  const int G = l >> 4, q16 = l & 15;

  for (int i = t; i < SEQ; i += 256)
    mlds[i] = mask[b * SEQ + i] * 1.44269504089f;   // log2(e) fold

  // Q fragments (pre-scaled in GEMM): lane holds Q[q][k0*32+G*8..+8]
  const int q0w = qt * 128 + w * 32;
  bf16x8 qf[2][2];
#pragma unroll
  for (int qi = 0; qi < 2; ++qi)
#pragma unroll
    for (int k0 = 0; k0 < 2; ++k0)
      qf[qi][k0] = *(const bf16x8*)(Qg + (size_t)(q0w + qi * 16 + q16) * HDIM + k0 * 32 + G * 8);

  f32x4 O[4][2];
#pragma unroll
  for (int dt = 0; dt < 4; dt++) { O[dt][0] = (f32x4){0,0,0,0}; O[dt][1] = (f32x4){0,0,0,0}; }
  float mrow[2] = {-3e38f, -3e38f}, lrow[2] = {0.f, 0.f};

  __syncthreads();   // mlds ready

  const int srow = t >> 2;
  const int sg0  = t & 3;
  uint16_t* Pw = &Plds[w][0];
  const int qsw = q16 & 7;          // row&7 is q16&7 for every frag row we read

#pragma unroll 1
  for (int kt = 0; kt < 16; ++kt) {
    // ---- stage K tile [k][d] and Vt tile [d][k], both swizzled ----
#pragma unroll
    for (int ia = 0; ia < 2; ia++) {
      int g  = sg0 + ia * 4;
      int gs = (g ^ (srow & 7)) & 7;
      bf16x8 kv = *(const bf16x8*)(Kg + (size_t)(kt * 64 + srow) * HDIM + g * 8);
      bf16x8 vv = *(const bf16x8*)(Vg + (size_t)srow * SEQ + kt * 64 + g * 8);
      *(bf16x8*)&Klds[srow * 64 + gs * 8] = kv;
      *(bf16x8*)&Vlds[srow * 64 + gs * 8] = vv;
    }
    __syncthreads();

    // mask values for this tile: k = jn*16 + G*4 + r  (broadcast across q16)
    f32x4 mv[4];
#pragma unroll
    for (int jn = 0; jn < 4; jn++)
      mv[jn] = *(const f32x4*)&mlds[kt * 64 + jn * 16 + G * 4];

#pragma unroll
    for (int qi = 0; qi < 2; ++qi) {
      // ---- S^T = mfma(K, Q): sc[jn][r] = S[q][k=jn*16+G*4+r] ----
      f32x4 sc[4];
#pragma unroll
      for (int jn = 0; jn < 4; jn++) sc[jn] = (f32x4){0,0,0,0};
#pragma unroll
      for (int k0 = 0; k0 < 2; ++k0)
#pragma unroll
        for (int jn = 0; jn < 4; jn++) {
          int kr = jn * 16 + q16;
          int gs = ((k0 * 4 + G) ^ qsw) & 7;
          bf16x8 kf = *(const bf16x8*)&Klds[kr * 64 + gs * 8];
          sc[jn] = __builtin_amdgcn_mfma_f32_16x16x32_bf16(kf, qf[qi][k0], sc[jn], 0, 0, 0);
        }

      // ---- online softmax over k (in-register + 2 shuffles) ----
      float pm = -3e38f;
#pragma unroll
      for (int jn = 0; jn < 4; jn++) {
        sc[jn] += mv[jn];
        pm = fmaxf(pm, fmaxf(fmaxf(sc[jn][0], sc[jn][1]), fmaxf(sc[jn][2], sc[jn][3])));
      }
      pm = fmaxf(pm, __shfl_xor(pm, 16));
      pm = fmaxf(pm, __shfl_xor(pm, 32));
      if (!__all(pm <= mrow[qi] + 11.0f)) {     // defer-max (log2 space)
        float mn = fmaxf(mrow[qi], pm);
        float fs = exp2fast(mrow[qi] - mn);
        mrow[qi] = mn;
        lrow[qi] *= fs;
#pragma unroll
        for (int dt = 0; dt < 4; dt++) O[dt][qi] *= fs;
      }
      float ps = 0.f;
      const int q = qi * 16 + q16;
#pragma unroll
      for (int jn = 0; jn < 4; jn++) {
        float p0 = exp2fast(sc[jn][0] - mrow[qi]);
        float p1 = exp2fast(sc[jn][1] - mrow[qi]);
        float p2 = exp2fast(sc[jn][2] - mrow[qi]);
        float p3 = exp2fast(sc[jn][3] - mrow[qi]);
        ps += (p0 + p1) + (p2 + p3);
        uint2 pw2;
        pw2.x = (uint32_t)f2bf(p0) | ((uint32_t)f2bf(p1) << 16);
        pw2.y = (uint32_t)f2bf(p2) | ((uint32_t)f2bf(p3) << 16);
        int g16 = (jn * 2 + (G >> 1)) ^ qsw;            // swizzled 16B granule
        *(uint2*)&Pw[q * 64 + g16 * 8 + (G & 1) * 4] = pw2;
      }
      ps += __shfl_xor(ps, 16);
      ps += __shfl_xor(ps, 32);
      lrow[qi] += ps;
    }

    // ---- O^T += V^T P (per-wave P: no barrier needed, lgkmcnt only) ----
#pragma unroll
    for (int ks = 0; ks < 2; ++ks) {
      int gp  = ks * 4 + G;
      int gsp = (gp ^ qsw) & 7;
      bf16x8 pf0 = *(const bf16x8*)&Pw[(q16     ) * 64 + gsp * 8];
      bf16x8 pf1 = *(const bf16x8*)&Pw[(16 + q16) * 64 + gsp * 8];
#pragma unroll
      for (int dt = 0; dt < 4; dt++) {
        int dr = dt * 16 + q16;
        bf16x8 vf = *(const bf16x8*)&Vlds[dr * 64 + gsp * 8];
        O[dt][0] = __builtin_amdgcn_mfma_f32_16x16x32_bf16(vf, pf0, O[dt][0], 0, 0, 0);
        O[dt][1] = __builtin_amdgcn_mfma_f32_16x16x32_bf16(vf, pf1, O[dt][1], 0, 0, 0);
      }
    }
    __syncthreads();   // all K/V reads done before next stage overwrites
  }

  // ---- epilogue: normalize + write out[b, s, h*64+d] as f32x4 ----
#pragma unroll
  for (int qi = 0; qi < 2; ++qi) {
    float inv = 1.0f / lrow[qi];
    int q = q0w + qi * 16 + q16;
    float* orow = out + (size_t)(b * SEQ + q) * HIDDEN + h * HDIM;
#pragma unroll
    for (int dt = 0; dt < 4; dt++) {
      f32x4 o4 = O[dt][qi] * inv;
      *(f32x4*)(orow + dt * 16 + G * 4) = o4;
    }
  }
}

// ================= host launcher =================
extern "C" void kernel_launch(void* const* d_in, const int* in_sizes, int n_in,
                              void* d_out, int out_size, void* d_ws, size_t ws_size,
                              hipStream_t stream) {
  const float* hs   = (const float*)d_in[0];
  const float* mask = (const float*)d_in[1];
  const float* Wq   = (const float*)d_in[2];
  const float* bq   = (const float*)d_in[3];
  const float* Wk   = (const float*)d_in[4];
  const float* bk   = (const float*)d_in[5];
  const float* Wv   = (const float*)d_in[6];
  const float* bv   = (const float*)d_in[7];
  float* out = (float*)d_out;

  // ws layout (bytes): hsb 16MB | wcat 6MB | Q 16MB | K 16MB | Vt 16MB
  uint16_t* hsb  = (uint16_t*)d_ws;
  uint16_t* wcat = (uint16_t*)((char*)d_ws + 16777216u);
  uint16_t* qbuf = (uint16_t*)((char*)d_ws + 23068672u);
  uint16_t* kbuf = (uint16_t*)((char*)d_ws + 39845888u);
  uint16_t* vtbf = (uint16_t*)((char*)d_ws + 56623104u);

  cvt_kernel<<<11264, 256, 0, stream>>>(hs, Wq, Wk, Wv, hsb, wcat);
  gemm_qkv<<<1536, 256, 0, stream>>>(hsb, wcat, bq, bk, bv, qbuf, kbuf, vtbf);
  attn_kernel<<<1024, 256, 0, stream>>>(qbuf, kbuf, vtbf, mask, out);
}

// Round 3
// 165.058 us; speedup vs baseline: 1.2209x; 1.0815x over previous
//
#include <hip/hip_runtime.h>
#include <stdint.h>
#include <stddef.h>

// ---------------- problem constants ----------------
#define HIDDEN 1024
#define NHEADS 16
#define HDIM   64
#define BS     8
#define SEQ    1024
#define MTOT   (BS*SEQ)               // 8192 rows
#define QKV_T  ((size_t)MTOT*HIDDEN)

typedef short    bf16x8 __attribute__((ext_vector_type(8)));
typedef float    f32x4  __attribute__((ext_vector_type(4)));
typedef uint16_t u16x4  __attribute__((ext_vector_type(4)));

__device__ __forceinline__ uint16_t f2bf(float f) {
  union { float f; uint32_t u; } c; c.f = f;
  uint32_t u = c.u + 0x7FFFu + ((c.u >> 16) & 1u);   // RNE
  return (uint16_t)(u >> 16);
}

__device__ __forceinline__ float exp2fast(float x) {
#if __has_builtin(__builtin_amdgcn_exp2f)
  return __builtin_amdgcn_exp2f(x);
#else
  return __expf(x * 0.69314718056f);
#endif
}

// async global->LDS, 16B per lane. LDS dest is wave-uniform base
// (HW writes lane i at base + i*16); global src is per-lane.
__device__ __forceinline__ void gload_lds16(const uint16_t* g, uint16_t* lds) {
  __builtin_amdgcn_global_load_lds(
      (const __attribute__((address_space(1))) uint32_t*)g,
      (__attribute__((address_space(3))) uint32_t*)lds, 16, 0, 0);
}

// ================= kernel 1: fp32 -> bf16 convert =================
__global__ __launch_bounds__(256) void cvt_kernel(
    const float* __restrict__ hs, const float* __restrict__ wq,
    const float* __restrict__ wk, const float* __restrict__ wv,
    uint16_t* __restrict__ hsb, uint16_t* __restrict__ wcat)
{
  const int i4 = blockIdx.x * 256 + threadIdx.x;      // 2,883,584 total
  f32x4 v;
  u16x4 o;
  if (i4 < 2097152) {                                  // hidden states
    v = *((const f32x4*)hs + i4);
    o[0]=f2bf(v[0]); o[1]=f2bf(v[1]); o[2]=f2bf(v[2]); o[3]=f2bf(v[3]);
    *((u16x4*)hsb + i4) = o;
  } else {                                             // weights
    int j4 = i4 - 2097152;                             // [0, 786432)
    int w  = j4 >> 18;                                  // 262144 float4 per W
    int r4 = j4 & 262143;
    const float* src = (w == 0) ? wq : ((w == 1) ? wk : wv);
    v = *((const f32x4*)src + r4);
    o[0]=f2bf(v[0]); o[1]=f2bf(v[1]); o[2]=f2bf(v[2]); o[3]=f2bf(v[3]);
    *((u16x4*)wcat + j4) = o;
  }
}

// ================= kernel 2: fused QKV GEMM (m97 structure) =================
// C[m,n] = sum_k hsb[m,k]*wcat[n,k] + bias[n]; n in [0,3072)
// 128x128 tile, BK=32, 4 waves, mfma 16x16x32 bf16.
// Staging: global_load_lds 16B, double-buffered, source pre-swizzled so the
// linear LDS write realizes slot = g ^ ((row>>1)&3) (involution).
__global__ __launch_bounds__(256) void gemm_qkv(
    const uint16_t* __restrict__ hsb, const uint16_t* __restrict__ wcat,
    const float* __restrict__ bq, const float* __restrict__ bk,
    const float* __restrict__ bv, uint16_t* __restrict__ qbuf,
    uint16_t* __restrict__ kbuf, uint16_t* __restrict__ vtbuf)
{
  __shared__ uint16_t Alds[2][128*32];
  __shared__ uint16_t Blds[2][128*32];

  const int bid = blockIdx.x;                 // 1536 blocks, %8==0 -> bijective
  const int wg  = (bid & 7) * 192 + (bid >> 3);   // XCD swizzle
  const int tm  = wg / 24, tn = wg % 24;
  const int m0  = tm * 128, n0 = tn * 128;
  const int t   = threadIdx.x;
  const int l   = t & 63, w = t >> 6;
  const int wm  = w >> 1, wn = w & 1;

  f32x4 acc[4][4];
#pragma unroll
  for (int i = 0; i < 4; i++)
#pragma unroll
    for (int j = 0; j < 4; j++) acc[i][j] = (f32x4){0.f,0.f,0.f,0.f};

  // staging geometry: instr n of wave w covers rows [(w*2+n)*16, +16),
  // lane l -> row += l>>2, src granule = (l&3) ^ ((row>>1)&3).
  const int r0   = (w * 2) * 16 + (l >> 2);
  const int r1   = (w * 2 + 1) * 16 + (l >> 2);
  const int g0s  = (l & 3) ^ ((r0 >> 1) & 3);
  const int g1s  = (l & 3) ^ ((r1 >> 1) & 3);
  const size_t aoff0 = (size_t)r0 * HIDDEN + g0s * 8;
  const size_t aoff1 = (size_t)r1 * HIDDEN + g1s * 8;

  auto STAGE = [&](int buf, int kt) {
    const uint16_t* Ab = hsb  + (size_t)m0 * HIDDEN + kt * 32;
    const uint16_t* Bb = wcat + (size_t)n0 * HIDDEN + kt * 32;
    gload_lds16(Ab + aoff0, &Alds[buf][(w * 2) * 512]);
    gload_lds16(Ab + aoff1, &Alds[buf][(w * 2 + 1) * 512]);
    gload_lds16(Bb + aoff0, &Blds[buf][(w * 2) * 512]);
    gload_lds16(Bb + aoff1, &Blds[buf][(w * 2 + 1) * 512]);
  };

  auto COMPUTE = [&](int buf) {
    bf16x8 af[4], bfr[4];
    const int G = l >> 4;
#pragma unroll
    for (int i = 0; i < 4; i++) {
      int ar = wm * 64 + i * 16 + (l & 15);
      int gs = (G ^ ((ar >> 1) & 3)) & 3;
      af[i] = *(const bf16x8*)&Alds[buf][ar * 32 + gs * 8];
    }
#pragma unroll
    for (int j = 0; j < 4; j++) {
      int br = wn * 64 + j * 16 + (l & 15);
      int gs = (G ^ ((br >> 1) & 3)) & 3;
      bfr[j] = *(const bf16x8*)&Blds[buf][br * 32 + gs * 8];
    }
#pragma unroll
    for (int i = 0; i < 4; i++)
#pragma unroll
      for (int j = 0; j < 4; j++)
        acc[i][j] = __builtin_amdgcn_mfma_f32_16x16x32_bf16(af[i], bfr[j], acc[i][j], 0, 0, 0);
  };

  STAGE(0, 0);
  __syncthreads();
#pragma unroll 1
  for (int kt = 0; kt < 32; ++kt) {
    int cur = kt & 1;
    if (kt < 31) STAGE(cur ^ 1, kt + 1);   // loads fly under the MFMAs
    COMPUTE(cur);
    __syncthreads();
  }

  // ---- epilogue ----
#pragma unroll
  for (int j = 0; j < 4; j++) {
    int n     = n0 + wn * 64 + j * 16 + (l & 15);
    int which = n >> 10, nn = n & 1023;    // uniform per block
    const float* bp = (which == 0) ? bq : ((which == 1) ? bk : bv);
    float bias = bp[nn];
    int hh = nn >> 6, dd = nn & 63;
#pragma unroll
    for (int i = 0; i < 4; i++) {
      if (which == 2) {
        // V transposed [b,h,d,s]: r indexes consecutive s -> one 8B store
        int m_  = m0 + wm * 64 + i * 16 + (l >> 4) * 4;
        int b_  = m_ >> 10, s_ = m_ & 1023;
        size_t bhh = (size_t)(b_ * NHEADS + hh);
        uint64_t pk =  (uint64_t)f2bf(acc[i][j][0] + bias)
                    | ((uint64_t)f2bf(acc[i][j][1] + bias) << 16)
                    | ((uint64_t)f2bf(acc[i][j][2] + bias) << 32)
                    | ((uint64_t)f2bf(acc[i][j][3] + bias) << 48);
        *(uint64_t*)&vtbuf[(bhh * HDIM + dd) * SEQ + s_] = pk;
      } else {
#pragma unroll
        for (int r = 0; r < 4; r++) {
          int m  = m0 + wm * 64 + i * 16 + (l >> 4) * 4 + r;
          int b_ = m >> 10, s_ = m & 1023;
          float val = acc[i][j][r] + bias;
          size_t bhh = (size_t)(b_ * NHEADS + hh);
          if (which == 0)        // Q: fold softmax scale * log2(e)
            qbuf[(bhh * SEQ + s_) * HDIM + dd] = f2bf(val * 0.18033688011112042f);
          else                   // K
            kbuf[(bhh * SEQ + s_) * HDIM + dd] = f2bf(val);
        }
      }
    }
  }
}

// ================= kernel 3: flash attention (swapped-operand) =================
__global__ __launch_bounds__(256) void attn_kernel(
    const uint16_t* __restrict__ qb, const uint16_t* __restrict__ kb,
    const uint16_t* __restrict__ vtb, const float* __restrict__ mask,
    float* __restrict__ out)
{
  __shared__ uint16_t Klds[64 * 64];
  __shared__ uint16_t Vlds[64 * 64];      // Vt tile: [d][k]
  __shared__ uint16_t Plds[4][32 * 64];   // per-wave P: [q][k]
  __shared__ float    mlds[SEQ];

  const int bid = blockIdx.x;                    // 1024 blocks, %8==0
  const int wg  = (bid & 7) * 128 + (bid >> 3);  // XCD swizzle
  const int bh  = wg >> 3;
  const int qt  = wg & 7;
  const int b   = bh >> 4, h = bh & 15;

  const uint16_t* Qg = qb  + (size_t)bh * SEQ * HDIM;
  const uint16_t* Kg = kb  + (size_t)bh * SEQ * HDIM;
  const uint16_t* Vg = vtb + (size_t)bh * HDIM * SEQ;

  const int t = threadIdx.x, l = t & 63, w = t >> 6;
  const int G = l >> 4, q16 = l & 15;

  for (int i = t; i < SEQ; i += 256)
    mlds[i] = mask[b * SEQ + i] * 1.44269504089f;   // log2(e) fold

  const int q0w = qt * 128 + w * 32;
  bf16x8 qf[2][2];
#pragma unroll
  for (int qi = 0; qi < 2; ++qi)
#pragma unroll
    for (int k0 = 0; k0 < 2; ++k0)
      qf[qi][k0] = *(const bf16x8*)(Qg + (size_t)(q0w + qi * 16 + q16) * HDIM + k0 * 32 + G * 8);

  f32x4 O[4][2];
#pragma unroll
  for (int dt = 0; dt < 4; dt++) { O[dt][0] = (f32x4){0,0,0,0}; O[dt][1] = (f32x4){0,0,0,0}; }
  float mrow[2] = {-3e38f, -3e38f}, lrow[2] = {0.f, 0.f};

  __syncthreads();   // mlds ready

  const int srow = t >> 2;
  const int sg0  = t & 3;
  uint16_t* Pw = &Plds[w][0];
  const int qsw = q16 & 7;

#pragma unroll 1
  for (int kt = 0; kt < 16; ++kt) {
#pragma unroll
    for (int ia = 0; ia < 2; ia++) {
      int g  = sg0 + ia * 4;
      int gs = (g ^ (srow & 7)) & 7;
      bf16x8 kv = *(const bf16x8*)(Kg + (size_t)(kt * 64 + srow) * HDIM + g * 8);
      bf16x8 vv = *(const bf16x8*)(Vg + (size_t)srow * SEQ + kt * 64 + g * 8);
      *(bf16x8*)&Klds[srow * 64 + gs * 8] = kv;
      *(bf16x8*)&Vlds[srow * 64 + gs * 8] = vv;
    }
    __syncthreads();

    f32x4 mv[4];
#pragma unroll
    for (int jn = 0; jn < 4; jn++)
      mv[jn] = *(const f32x4*)&mlds[kt * 64 + jn * 16 + G * 4];

#pragma unroll
    for (int qi = 0; qi < 2; ++qi) {
      f32x4 sc[4];
#pragma unroll
      for (int jn = 0; jn < 4; jn++) sc[jn] = (f32x4){0,0,0,0};
      __builtin_amdgcn_s_setprio(1);
#pragma unroll
      for (int k0 = 0; k0 < 2; ++k0)
#pragma unroll
        for (int jn = 0; jn < 4; jn++) {
          int kr = jn * 16 + q16;
          int gs = ((k0 * 4 + G) ^ qsw) & 7;
          bf16x8 kf = *(const bf16x8*)&Klds[kr * 64 + gs * 8];
          sc[jn] = __builtin_amdgcn_mfma_f32_16x16x32_bf16(kf, qf[qi][k0], sc[jn], 0, 0, 0);
        }
      __builtin_amdgcn_s_setprio(0);

      float pm = -3e38f;
#pragma unroll
      for (int jn = 0; jn < 4; jn++) {
        sc[jn] += mv[jn];
        pm = fmaxf(pm, fmaxf(fmaxf(sc[jn][0], sc[jn][1]), fmaxf(sc[jn][2], sc[jn][3])));
      }
      pm = fmaxf(pm, __shfl_xor(pm, 16));
      pm = fmaxf(pm, __shfl_xor(pm, 32));
      if (!__all(pm <= mrow[qi] + 11.0f)) {     // defer-max (log2 space)
        float mn = fmaxf(mrow[qi], pm);
        float fs = exp2fast(mrow[qi] - mn);
        mrow[qi] = mn;
        lrow[qi] *= fs;
#pragma unroll
        for (int dt = 0; dt < 4; dt++) O[dt][qi] *= fs;
      }
      float ps = 0.f;
      const int q = qi * 16 + q16;
#pragma unroll
      for (int jn = 0; jn < 4; jn++) {
        float p0 = exp2fast(sc[jn][0] - mrow[qi]);
        float p1 = exp2fast(sc[jn][1] - mrow[qi]);
        float p2 = exp2fast(sc[jn][2] - mrow[qi]);
        float p3 = exp2fast(sc[jn][3] - mrow[qi]);
        ps += (p0 + p1) + (p2 + p3);
        uint2 pw2;
        pw2.x = (uint32_t)f2bf(p0) | ((uint32_t)f2bf(p1) << 16);
        pw2.y = (uint32_t)f2bf(p2) | ((uint32_t)f2bf(p3) << 16);
        int g16 = (jn * 2 + (G >> 1)) ^ qsw;
        *(uint2*)&Pw[q * 64 + g16 * 8 + (G & 1) * 4] = pw2;
      }
      ps += __shfl_xor(ps, 16);
      ps += __shfl_xor(ps, 32);
      lrow[qi] += ps;
    }

    __builtin_amdgcn_s_setprio(1);
#pragma unroll
    for (int ks = 0; ks < 2; ++ks) {
      int gp  = ks * 4 + G;
      int gsp = (gp ^ qsw) & 7;
      bf16x8 pf0 = *(const bf16x8*)&Pw[(q16     ) * 64 + gsp * 8];
      bf16x8 pf1 = *(const bf16x8*)&Pw[(16 + q16) * 64 + gsp * 8];
#pragma unroll
      for (int dt = 0; dt < 4; dt++) {
        int dr = dt * 16 + q16;
        bf16x8 vf = *(const bf16x8*)&Vlds[dr * 64 + gsp * 8];
        O[dt][0] = __builtin_amdgcn_mfma_f32_16x16x32_bf16(vf, pf0, O[dt][0], 0, 0, 0);
        O[dt][1] = __builtin_amdgcn_mfma_f32_16x16x32_bf16(vf, pf1, O[dt][1], 0, 0, 0);
      }
    }
    __builtin_amdgcn_s_setprio(0);
    __syncthreads();
  }

#pragma unroll
  for (int qi = 0; qi < 2; ++qi) {
    float inv = 1.0f / lrow[qi];
    int q = q0w + qi * 16 + q16;
    float* orow = out + (size_t)(b * SEQ + q) * HIDDEN + h * HDIM;
#pragma unroll
    for (int dt = 0; dt < 4; dt++) {
      f32x4 o4 = O[dt][qi] * inv;
      *(f32x4*)(orow + dt * 16 + G * 4) = o4;
    }
  }
}

// ================= host launcher =================
extern "C" void kernel_launch(void* const* d_in, const int* in_sizes, int n_in,
                              void* d_out, int out_size, void* d_ws, size_t ws_size,
                              hipStream_t stream) {
  const float* hs   = (const float*)d_in[0];
  const float* mask = (const float*)d_in[1];
  const float* Wq   = (const float*)d_in[2];
  const float* bq   = (const float*)d_in[3];
  const float* Wk   = (const float*)d_in[4];
  const float* bk   = (const float*)d_in[5];
  const float* Wv   = (const float*)d_in[6];
  const float* bv   = (const float*)d_in[7];
  float* out = (float*)d_out;

  // ws layout (bytes): hsb 16MB | wcat 6MB | Q 16MB | K 16MB | Vt 16MB
  uint16_t* hsb  = (uint16_t*)d_ws;
  uint16_t* wcat = (uint16_t*)((char*)d_ws + 16777216u);
  uint16_t* qbuf = (uint16_t*)((char*)d_ws + 23068672u);
  uint16_t* kbuf = (uint16_t*)((char*)d_ws + 39845888u);
  uint16_t* vtbf = (uint16_t*)((char*)d_ws + 56623104u);

  cvt_kernel<<<11264, 256, 0, stream>>>(hs, Wq, Wk, Wv, hsb, wcat);
  gemm_qkv<<<1536, 256, 0, stream>>>(hsb, wcat, bq, bk, bv, qbuf, kbuf, vtbf);
  attn_kernel<<<1024, 256, 0, stream>>>(qbuf, kbuf, vtbf, mask, out);
}

// Round 4
// 148.692 us; speedup vs baseline: 1.3552x; 1.1101x over previous
//
#include <hip/hip_runtime.h>
#include <stdint.h>
#include <stddef.h>

// ---------------- problem constants ----------------
#define HIDDEN 1024
#define NHEADS 16
#define HDIM   64
#define BS     8
#define SEQ    1024
#define MTOT   (BS*SEQ)               // 8192 rows
#define QKV_T  ((size_t)MTOT*HIDDEN)

typedef short    bf16x8 __attribute__((ext_vector_type(8)));
typedef float    f32x4  __attribute__((ext_vector_type(4)));
typedef uint16_t u16x4  __attribute__((ext_vector_type(4)));

__device__ __forceinline__ uint16_t f2bf(float f) {
  union { float f; uint32_t u; } c; c.f = f;
  uint32_t u = c.u + 0x7FFFu + ((c.u >> 16) & 1u);   // RNE
  return (uint16_t)(u >> 16);
}

// packed f32x2 -> bf16x2 (HW RNE), one VALU op for two values
__device__ __forceinline__ uint32_t cvt_pk_bf16(float lo, float hi) {
  uint32_t r;
  asm("v_cvt_pk_bf16_f32 %0, %1, %2" : "=v"(r) : "v"(lo), "v"(hi));
  return r;
}

__device__ __forceinline__ float exp2fast(float x) {
#if __has_builtin(__builtin_amdgcn_exp2f)
  return __builtin_amdgcn_exp2f(x);
#else
  return __expf(x * 0.69314718056f);
#endif
}

// async global->LDS, 16B per lane. LDS dest is wave-uniform base
// (HW writes lane i at base + i*16); global src is per-lane.
__device__ __forceinline__ void gload_lds16(const uint16_t* g, uint16_t* lds) {
  __builtin_amdgcn_global_load_lds(
      (const __attribute__((address_space(1))) uint32_t*)g,
      (__attribute__((address_space(3))) uint32_t*)lds, 16, 0, 0);
}

// ================= kernel 1: fp32 -> bf16 convert =================
__global__ __launch_bounds__(256) void cvt_kernel(
    const float* __restrict__ hs, const float* __restrict__ wq,
    const float* __restrict__ wk, const float* __restrict__ wv,
    uint16_t* __restrict__ hsb, uint16_t* __restrict__ wcat)
{
  const int i4 = blockIdx.x * 256 + threadIdx.x;      // 2,883,584 total
  f32x4 v;
  u16x4 o;
  if (i4 < 2097152) {                                  // hidden states
    v = *((const f32x4*)hs + i4);
    o[0]=f2bf(v[0]); o[1]=f2bf(v[1]); o[2]=f2bf(v[2]); o[3]=f2bf(v[3]);
    *((u16x4*)hsb + i4) = o;
  } else {                                             // weights
    int j4 = i4 - 2097152;                             // [0, 786432)
    int w  = j4 >> 18;                                  // 262144 float4 per W
    int r4 = j4 & 262143;
    const float* src = (w == 0) ? wq : ((w == 1) ? wk : wv);
    v = *((const f32x4*)src + r4);
    o[0]=f2bf(v[0]); o[1]=f2bf(v[1]); o[2]=f2bf(v[2]); o[3]=f2bf(v[3]);
    *((u16x4*)wcat + j4) = o;
  }
}

// ================= kernel 2: fused QKV GEMM (m97 structure) =================
// C[m,n] = sum_k hsb[m,k]*wcat[n,k] + bias[n]; n in [0,3072)
// 128x128 tile, BK=32, 4 waves, mfma 16x16x32 bf16.
// Staging: global_load_lds 16B, double-buffered, source pre-swizzled so the
// linear LDS write realizes slot = g ^ ((row>>1)&3) (involution).
__global__ __launch_bounds__(256) void gemm_qkv(
    const uint16_t* __restrict__ hsb, const uint16_t* __restrict__ wcat,
    const float* __restrict__ bq, const float* __restrict__ bk,
    const float* __restrict__ bv, uint16_t* __restrict__ qbuf,
    uint16_t* __restrict__ kbuf, uint16_t* __restrict__ vtbuf)
{
  __shared__ uint16_t Alds[2][128*32];
  __shared__ uint16_t Blds[2][128*32];

  const int bid = blockIdx.x;                 // 1536 blocks, %8==0 -> bijective
  const int wg  = (bid & 7) * 192 + (bid >> 3);   // XCD swizzle
  const int tm  = wg / 24, tn = wg % 24;
  const int m0  = tm * 128, n0 = tn * 128;
  const int t   = threadIdx.x;
  const int l   = t & 63, w = t >> 6;
  const int wm  = w >> 1, wn = w & 1;

  f32x4 acc[4][4];
#pragma unroll
  for (int i = 0; i < 4; i++)
#pragma unroll
    for (int j = 0; j < 4; j++) acc[i][j] = (f32x4){0.f,0.f,0.f,0.f};

  // staging geometry: instr n of wave w covers rows [(w*2+n)*16, +16),
  // lane l -> row += l>>2, src granule = (l&3) ^ ((row>>1)&3).
  const int r0   = (w * 2) * 16 + (l >> 2);
  const int r1   = (w * 2 + 1) * 16 + (l >> 2);
  const int g0s  = (l & 3) ^ ((r0 >> 1) & 3);
  const int g1s  = (l & 3) ^ ((r1 >> 1) & 3);
  const size_t aoff0 = (size_t)r0 * HIDDEN + g0s * 8;
  const size_t aoff1 = (size_t)r1 * HIDDEN + g1s * 8;

  auto STAGE = [&](int buf, int kt) {
    const uint16_t* Ab = hsb  + (size_t)m0 * HIDDEN + kt * 32;
    const uint16_t* Bb = wcat + (size_t)n0 * HIDDEN + kt * 32;
    gload_lds16(Ab + aoff0, &Alds[buf][(w * 2) * 512]);
    gload_lds16(Ab + aoff1, &Alds[buf][(w * 2 + 1) * 512]);
    gload_lds16(Bb + aoff0, &Blds[buf][(w * 2) * 512]);
    gload_lds16(Bb + aoff1, &Blds[buf][(w * 2 + 1) * 512]);
  };

  auto COMPUTE = [&](int buf) {
    bf16x8 af[4], bfr[4];
    const int G = l >> 4;
#pragma unroll
    for (int i = 0; i < 4; i++) {
      int ar = wm * 64 + i * 16 + (l & 15);
      int gs = (G ^ ((ar >> 1) & 3)) & 3;
      af[i] = *(const bf16x8*)&Alds[buf][ar * 32 + gs * 8];
    }
#pragma unroll
    for (int j = 0; j < 4; j++) {
      int br = wn * 64 + j * 16 + (l & 15);
      int gs = (G ^ ((br >> 1) & 3)) & 3;
      bfr[j] = *(const bf16x8*)&Blds[buf][br * 32 + gs * 8];
    }
#pragma unroll
    for (int i = 0; i < 4; i++)
#pragma unroll
      for (int j = 0; j < 4; j++)
        acc[i][j] = __builtin_amdgcn_mfma_f32_16x16x32_bf16(af[i], bfr[j], acc[i][j], 0, 0, 0);
  };

  STAGE(0, 0);
  __syncthreads();
#pragma unroll 1
  for (int kt = 0; kt < 32; ++kt) {
    int cur = kt & 1;
    if (kt < 31) STAGE(cur ^ 1, kt + 1);   // loads fly under the MFMAs
    COMPUTE(cur);
    __syncthreads();
  }

  // ---- epilogue ----
#pragma unroll
  for (int j = 0; j < 4; j++) {
    int n     = n0 + wn * 64 + j * 16 + (l & 15);
    int which = n >> 10, nn = n & 1023;    // uniform per block
    const float* bp = (which == 0) ? bq : ((which == 1) ? bk : bv);
    float bias = bp[nn];
    int hh = nn >> 6, dd = nn & 63;
#pragma unroll
    for (int i = 0; i < 4; i++) {
      if (which == 2) {
        // V transposed [b,h,d,s]: r indexes consecutive s -> one 8B store
        int m_  = m0 + wm * 64 + i * 16 + (l >> 4) * 4;
        int b_  = m_ >> 10, s_ = m_ & 1023;
        size_t bhh = (size_t)(b_ * NHEADS + hh);
        uint2 pk;
        pk.x = cvt_pk_bf16(acc[i][j][0] + bias, acc[i][j][1] + bias);
        pk.y = cvt_pk_bf16(acc[i][j][2] + bias, acc[i][j][3] + bias);
        *(uint2*)&vtbuf[(bhh * HDIM + dd) * SEQ + s_] = pk;
      } else {
#pragma unroll
        for (int r = 0; r < 4; r++) {
          int m  = m0 + wm * 64 + i * 16 + (l >> 4) * 4 + r;
          int b_ = m >> 10, s_ = m & 1023;
          float val = acc[i][j][r] + bias;
          size_t bhh = (size_t)(b_ * NHEADS + hh);
          if (which == 0)        // Q: fold softmax scale * log2(e)
            qbuf[(bhh * SEQ + s_) * HDIM + dd] = f2bf(val * 0.18033688011112042f);
          else                   // K
            kbuf[(bhh * SEQ + s_) * HDIM + dd] = f2bf(val);
        }
      }
    }
  }
}

// ================= kernel 3: flash attention (swapped-operand) =================
// Block: one (b,h) x 128 Q-rows; 4 waves x QBLK=32. KVBLK=64.
// S^T = mfma(K,Q); k-reduction in-register + shfl_xor(16,32).
// O^T = mfma(Vt,P); Vt pre-transposed by GEMM.
// K/V staged via global_load_lds with pre-swizzled source: lane l covers
// row = rbase + (l>>3), slot = l&7, src granule = (l&7)^(l>>3); realizes
// LDS slot = g ^ (row&7) -> quarter-wave writes hit all 32 banks.
__global__ __launch_bounds__(256) void attn_kernel(
    const uint16_t* __restrict__ qb, const uint16_t* __restrict__ kb,
    const uint16_t* __restrict__ vtb, const float* __restrict__ mask,
    float* __restrict__ out)
{
  __shared__ uint16_t Klds[64 * 64];
  __shared__ uint16_t Vlds[64 * 64];      // Vt tile: [d][k]
  __shared__ uint16_t Plds[4][32 * 64];   // per-wave P: [q][k]
  __shared__ float    mlds[SEQ];

  const int bid = blockIdx.x;                    // 1024 blocks, %8==0
  const int wg  = (bid & 7) * 128 + (bid >> 3);  // XCD swizzle
  const int bh  = wg >> 3;
  const int qt  = wg & 7;
  const int b   = bh >> 4, h = bh & 15;

  const uint16_t* Qg = qb  + (size_t)bh * SEQ * HDIM;
  const uint16_t* Kg = kb  + (size_t)bh * SEQ * HDIM;
  const uint16_t* Vg = vtb + (size_t)bh * HDIM * SEQ;

  const int t = threadIdx.x, l = t & 63, w = t >> 6;
  const int G = l >> 4, q16 = l & 15;

  for (int i = t; i < SEQ; i += 256)
    mlds[i] = mask[b * SEQ + i] * 1.44269504089f;   // log2(e) fold

  const int q0w = qt * 128 + w * 32;
  bf16x8 qf[2][2];
#pragma unroll
  for (int qi = 0; qi < 2; ++qi)
#pragma unroll
    for (int k0 = 0; k0 < 2; ++k0)
      qf[qi][k0] = *(const bf16x8*)(Qg + (size_t)(q0w + qi * 16 + q16) * HDIM + k0 * 32 + G * 8);

  f32x4 O[4][2];
#pragma unroll
  for (int dt = 0; dt < 4; dt++) { O[dt][0] = (f32x4){0,0,0,0}; O[dt][1] = (f32x4){0,0,0,0}; }
  float mrow[2] = {-3e38f, -3e38f}, lrow[2] = {0.f, 0.f};

  __syncthreads();   // mlds ready

  // staging geometry (global_load_lds, per-lane swizzled source)
  const int srow8 = l >> 3;                 // row within 8-row group
  const int gsrc  = (l & 7) ^ srow8;        // source granule (involution)
  uint16_t* Pw = &Plds[w][0];
  const int qsw = q16 & 7;

#pragma unroll 1
  for (int kt = 0; kt < 16; ++kt) {
#pragma unroll
    for (int ia = 0; ia < 2; ia++) {
      const int rbase = ia * 32 + w * 8;    // wave-uniform LDS base row
      const int row   = rbase + srow8;
      gload_lds16(Kg + (size_t)(kt * 64 + row) * HDIM + gsrc * 8, &Klds[rbase * 64]);
      gload_lds16(Vg + (size_t)row * SEQ + kt * 64 + gsrc * 8,    &Vlds[rbase * 64]);
    }
    __syncthreads();

    f32x4 mv[4];
#pragma unroll
    for (int jn = 0; jn < 4; jn++)
      mv[jn] = *(const f32x4*)&mlds[kt * 64 + jn * 16 + G * 4];

#pragma unroll
    for (int qi = 0; qi < 2; ++qi) {
      f32x4 sc[4];
#pragma unroll
      for (int jn = 0; jn < 4; jn++) sc[jn] = (f32x4){0,0,0,0};
#pragma unroll
      for (int k0 = 0; k0 < 2; ++k0)
#pragma unroll
        for (int jn = 0; jn < 4; jn++) {
          int kr = jn * 16 + q16;
          int gs = ((k0 * 4 + G) ^ qsw) & 7;
          bf16x8 kf = *(const bf16x8*)&Klds[kr * 64 + gs * 8];
          sc[jn] = __builtin_amdgcn_mfma_f32_16x16x32_bf16(kf, qf[qi][k0], sc[jn], 0, 0, 0);
        }

      float pm = -3e38f;
#pragma unroll
      for (int jn = 0; jn < 4; jn++) {
        sc[jn] += mv[jn];
        pm = fmaxf(pm, fmaxf(fmaxf(sc[jn][0], sc[jn][1]), fmaxf(sc[jn][2], sc[jn][3])));
      }
      pm = fmaxf(pm, __shfl_xor(pm, 16));
      pm = fmaxf(pm, __shfl_xor(pm, 32));
      if (!__all(pm <= mrow[qi] + 11.0f)) {     // defer-max (log2 space)
        float mn = fmaxf(mrow[qi], pm);
        float fs = exp2fast(mrow[qi] - mn);
        mrow[qi] = mn;
        lrow[qi] *= fs;
#pragma unroll
        for (int dt = 0; dt < 4; dt++) O[dt][qi] *= fs;
      }
      float ps = 0.f;
      const int q = qi * 16 + q16;
#pragma unroll
      for (int jn = 0; jn < 4; jn++) {
        float p0 = exp2fast(sc[jn][0] - mrow[qi]);
        float p1 = exp2fast(sc[jn][1] - mrow[qi]);
        float p2 = exp2fast(sc[jn][2] - mrow[qi]);
        float p3 = exp2fast(sc[jn][3] - mrow[qi]);
        ps += (p0 + p1) + (p2 + p3);
        uint2 pw2;
        pw2.x = cvt_pk_bf16(p0, p1);
        pw2.y = cvt_pk_bf16(p2, p3);
        int g16 = (jn * 2 + (G >> 1)) ^ qsw;
        *(uint2*)&Pw[q * 64 + g16 * 8 + (G & 1) * 4] = pw2;
      }
      ps += __shfl_xor(ps, 16);
      ps += __shfl_xor(ps, 32);
      lrow[qi] += ps;
    }

#pragma unroll
    for (int ks = 0; ks < 2; ++ks) {
      int gp  = ks * 4 + G;
      int gsp = (gp ^ qsw) & 7;
      bf16x8 pf0 = *(const bf16x8*)&Pw[(q16     ) * 64 + gsp * 8];
      bf16x8 pf1 = *(const bf16x8*)&Pw[(16 + q16) * 64 + gsp * 8];
#pragma unroll
      for (int dt = 0; dt < 4; dt++) {
        int dr = dt * 16 + q16;
        bf16x8 vf = *(const bf16x8*)&Vlds[dr * 64 + gsp * 8];
        O[dt][0] = __builtin_amdgcn_mfma_f32_16x16x32_bf16(vf, pf0, O[dt][0], 0, 0, 0);
        O[dt][1] = __builtin_amdgcn_mfma_f32_16x16x32_bf16(vf, pf1, O[dt][1], 0, 0, 0);
      }
    }
    __syncthreads();   // all K/V/P reads done before next stage overwrites
  }

#pragma unroll
  for (int qi = 0; qi < 2; ++qi) {
    float inv = 1.0f / lrow[qi];
    int q = q0w + qi * 16 + q16;
    float* orow = out + (size_t)(b * SEQ + q) * HIDDEN + h * HDIM;
#pragma unroll
    for (int dt = 0; dt < 4; dt++) {
      f32x4 o4 = O[dt][qi] * inv;
      *(f32x4*)(orow + dt * 16 + G * 4) = o4;
    }
  }
}

// ================= host launcher =================
extern "C" void kernel_launch(void* const* d_in, const int* in_sizes, int n_in,
                              void* d_out, int out_size, void* d_ws, size_t ws_size,
                              hipStream_t stream) {
  const float* hs   = (const float*)d_in[0];
  const float* mask = (const float*)d_in[1];
  const float* Wq   = (const float*)d_in[2];
  const float* bq   = (const float*)d_in[3];
  const float* Wk   = (const float*)d_in[4];
  const float* bk   = (const float*)d_in[5];
  const float* Wv   = (const float*)d_in[6];
  const float* bv   = (const float*)d_in[7];
  float* out = (float*)d_out;

  // ws layout (bytes): hsb 16MB | wcat 6MB | Q 16MB | K 16MB | Vt 16MB
  uint16_t* hsb  = (uint16_t*)d_ws;
  uint16_t* wcat = (uint16_t*)((char*)d_ws + 16777216u);
  uint16_t* qbuf = (uint16_t*)((char*)d_ws + 23068672u);
  uint16_t* kbuf = (uint16_t*)((char*)d_ws + 39845888u);
  uint16_t* vtbf = (uint16_t*)((char*)d_ws + 56623104u);

  cvt_kernel<<<11264, 256, 0, stream>>>(hs, Wq, Wk, Wv, hsb, wcat);
  gemm_qkv<<<1536, 256, 0, stream>>>(hsb, wcat, bq, bk, bv, qbuf, kbuf, vtbf);
  attn_kernel<<<1024, 256, 0, stream>>>(qbuf, kbuf, vtbf, mask, out);
}